// Round 5
// baseline (143.348 us; speedup 1.0000x reference)
//
#include <hip/hip_runtime.h>

#define HH 1024
#define WW 1024
#define BB 8
#define WORDS_X 16               /* 1024 / 64 bit-words per row        */
#define NPART 4096               /* ls_loss blocks / partials          */

// ---------------------------------------------------------------------------
// Kernel 1: edge bitmask. target in {0,1} so the 11x11 Laplacian test
// (121*t_c != window_sum, zero-padded) reduces to pure bit logic:
//   t_c=0: edge <=> OR of window == 1
//   t_c=1: edge <=> AND of window == 0   (OOB pad counts as 0)
// Bits packed via __ballot (64 px per coalesced wave load).
// ---------------------------------------------------------------------------
__global__ __launch_bounds__(256) void ls_edge(const int* __restrict__ tgt,
                                               unsigned long long* __restrict__ eb,
                                               unsigned long long* __restrict__ tb) {
    __shared__ unsigned long long s_w[74][3];   // [staged row][left|mid|right]
    __shared__ unsigned long long s_oh[74], s_ah[74];

    const int tid  = threadIdx.x;
    const int lane = tid & 63;
    const int wv   = tid >> 6;
    const int b  = blockIdx.z;
    const int ty = blockIdx.y * 64;
    const int tx = blockIdx.x * 64;
    const int* tp = tgt + (size_t)b * HH * WW;

    // Stage 74 rows x 3 words of packed target bits (OOB -> 0).
    for (int task = wv; task < 74 * 3; task += 4) {
        int r = task / 3, k = task - 3 * r;      // k: 0=left,1=mid,2=right word
        int gy = ty - 5 + r;
        int gx = tx + (k - 1) * 64 + lane;
        int v = 0;
        if ((unsigned)gy < HH && (unsigned)gx < WW) v = tp[(size_t)gy * WW + gx];
        unsigned long long m = __ballot(v != 0);
        if (lane == 0) s_w[r][k] = m;
    }
    __syncthreads();

    // Horizontal 11-window OR/AND per staged row (funnel shifts over 192b).
    if (tid < 74) {
        unsigned long long wl = s_w[tid][0], wm = s_w[tid][1], wr = s_w[tid][2];
        unsigned long long oh = wm, ah = wm;
#pragma unroll
        for (int d = 1; d <= 5; ++d) {
            unsigned long long vr = (wm >> d) | (wr << (64 - d));
            unsigned long long vl = (wm << d) | (wl >> (64 - d));
            oh |= vr | vl;
            ah &= vr & vl;
        }
        s_oh[tid] = oh;
        s_ah[tid] = ah;
    }
    __syncthreads();

    // Vertical 11-window OR/AND; emit edge + center-target bit-words.
    if (tid < 64) {
        unsigned long long ov = 0, av = ~0ULL;
#pragma unroll
        for (int k = 0; k < 11; ++k) { ov |= s_oh[tid + k]; av &= s_ah[tid + k]; }
        unsigned long long tc = s_w[tid + 5][1];
        unsigned long long e  = (ov & ~tc) | (~av & tc);
        size_t w = (size_t)((b << 10) + ty + tid) * WORDS_X + blockIdx.x;
        eb[w] = e;
        tb[w] = tc;
    }
}

// ---------------------------------------------------------------------------
// Kernel 2: barrier-free streaming loss. 8 px/thread, 2048 px/block.
// ---------------------------------------------------------------------------
__global__ __launch_bounds__(256) void ls_loss(const float* __restrict__ x,
                                               const unsigned long long* __restrict__ eb,
                                               const unsigned long long* __restrict__ tb,
                                               float* __restrict__ partial) {
    __shared__ float s_red[4];
    const int tid = threadIdx.x;
    const int blk = blockIdx.x;              // 4096 blocks; 512 per image
    const int b   = blk >> 9;
    const int off = ((blk & 511) << 11) + (tid << 3);

    const float* x0p = x + (size_t)b * 2 * HH * WW + off;
    const float* x1p = x0p + (size_t)HH * WW;
    float4 a0 = ((const float4*)x0p)[0], a1 = ((const float4*)x0p)[1];
    float4 b0 = ((const float4*)x1p)[0], b1 = ((const float4*)x1p)[1];

    size_t widx = ((size_t)b * HH * WW + off) >> 6;
    unsigned int sh = off & 63;
    unsigned int e8 = (unsigned int)(eb[widx] >> sh) & 0xffu;
    unsigned int t8 = (unsigned int)(tb[widx] >> sh) & 0xffu;

    float f0[8] = {a0.x, a0.y, a0.z, a0.w, a1.x, a1.y, a1.z, a1.w};
    float f1[8] = {b0.x, b0.y, b0.z, b0.w, b1.x, b1.y, b1.z, b1.w};

    float acc = 0.f;
#pragma unroll
    for (int j = 0; j < 8; ++j) {
        int t = (t8 >> j) & 1;
        int e = (e8 >> j) & 1;
        float v0 = f0[j], v1 = f1[j];
        float m   = fmaxf(v0, v1);
        float lse = m + __logf(1.0f + __expf(-fabsf(v0 - v1)));
        float lp0 = v0 - lse, lp1 = v1 - lse;
        float lpt = t ? lp1 : lp0;
        float lpo = t ? lp0 : lp1;
        acc += e ? (0.95f * lpt + 0.1f * lpo) : lpt;
    }

#pragma unroll
    for (int offl = 32; offl > 0; offl >>= 1) acc += __shfl_down(acc, offl, 64);
    if ((tid & 63) == 0) s_red[tid >> 6] = acc;
    __syncthreads();
    if (tid == 0) partial[blk] = s_red[0] + s_red[1] + s_red[2] + s_red[3];
}

__global__ __launch_bounds__(256) void ls_final(const float* __restrict__ partial,
                                                float* __restrict__ out) {
    __shared__ double s_red[4];
    const int tid = threadIdx.x;
    double s = 0.0;
    for (int i = tid; i < NPART; i += 256) s += (double)partial[i];
#pragma unroll
    for (int off = 32; off > 0; off >>= 1) s += __shfl_down(s, off, 64);
    if ((tid & 63) == 0) s_red[tid >> 6] = s;
    __syncthreads();
    if (tid == 0) {
        double total = s_red[0] + s_red[1] + s_red[2] + s_red[3];
        out[0] = (float)(-total * (1.0 / (8.0 * 1024.0 * 1024.0)));
    }
}

extern "C" void kernel_launch(void* const* d_in, const int* in_sizes, int n_in,
                              void* d_out, int out_size, void* d_ws, size_t ws_size,
                              hipStream_t stream) {
    const float* x  = (const float*)d_in[0];
    const int* tgt  = (const int*)d_in[1];

    // Workspace layout: [partials 16KB][E bitmask 1MB][T bitmask 1MB]
    float* partial = (float*)d_ws;
    unsigned long long* eb = (unsigned long long*)((char*)d_ws + (64 << 10));
    unsigned long long* tb = eb + (size_t)BB * HH * WORDS_X;

    hipLaunchKernelGGL(ls_edge, dim3(16, 16, 8), dim3(256), 0, stream, tgt, eb, tb);
    hipLaunchKernelGGL(ls_loss, dim3(NPART), dim3(256), 0, stream, x, eb, tb, partial);
    hipLaunchKernelGGL(ls_final, dim3(1), dim3(256), 0, stream, partial, (float*)d_out);
}

// Round 6
// 118.582 us; speedup vs baseline: 1.2089x; 1.2089x over previous
//
#include <hip/hip_runtime.h>

#define HH 1024
#define WW 1024
#define BB 8
#define WORDS_X 16             /* 64-px bit-words per row */
#define NPART 2048

typedef unsigned long long u64;

// ---------------------------------------------------------------------------
// Kernel 1: pack target (int32 0/1) into a bit image. Pure stream: per wave,
// 8 independent coalesced 256B loads -> 8 ballots -> one 64B store.
// ---------------------------------------------------------------------------
__global__ __launch_bounds__(256) void ls_pack(const int* __restrict__ tgt,
                                               u64* __restrict__ bits) {
    const int lane = threadIdx.x & 63;
    const size_t wv = ((size_t)blockIdx.x * 256 + threadIdx.x) >> 6;
    const size_t wbase = wv * 8;                 // first of 8 words (512 px)
    const int* p = tgt + wbase * 64 + lane;

    int v[8];
#pragma unroll
    for (int j = 0; j < 8; ++j) v[j] = p[j * 64];

    u64 mine = 0;
#pragma unroll
    for (int j = 0; j < 8; ++j) {
        u64 m = __ballot(v[j] != 0);
        if (lane == j) mine = m;
    }
    if (lane < 8) bits[wbase + lane] = mine;
}

// ---------------------------------------------------------------------------
// Kernel 2: fused edge-from-bits + loss. 64x64 tile per block.
//   t_c=0: edge <=> OR of 11x11 window ; t_c=1: edge <=> !(AND of window)
// (exactly 121*t_c != window_sum with zero padding: OOB rows/words = 0.)
// ---------------------------------------------------------------------------
__global__ __launch_bounds__(256) void ls_loss(const float* __restrict__ x,
                                               const u64* __restrict__ bits,
                                               float* __restrict__ partial) {
    __shared__ u64 s_w[74][3];
    __shared__ u64 s_oh[74], s_ah[74], s_e[64];
    __shared__ float s_red[4];

    const int tid = threadIdx.x;
    const int b  = blockIdx.z;
    const int ty = blockIdx.y * 64;
    const int wx = blockIdx.x;               // word index == tile col block

    // ---- Issue x loads first: 16 px/thread (one row, cols c0..c0+15) ----
    const int row = tid >> 2;
    const int c0  = (tid & 3) << 4;
    const float* x0p = x + ((size_t)b * 2 + 0) * HH * WW
                         + (size_t)(ty + row) * WW + (wx << 6) + c0;
    const float* x1p = x0p + (size_t)HH * WW;
    float4 xv0[4], xv1[4];
#pragma unroll
    for (int q = 0; q < 4; ++q) xv0[q] = ((const float4*)x0p)[q];
#pragma unroll
    for (int q = 0; q < 4; ++q) xv1[q] = ((const float4*)x1p)[q];

    // ---- Stage 74 rows x 3 bit-words (one 8B load per thread, OOB->0) ----
    if (tid < 222) {
        int r = tid / 3, k = tid - 3 * r;
        int gy = ty - 5 + r;
        int wi = wx - 1 + k;
        u64 v = 0;
        if ((unsigned)gy < HH && (unsigned)wi < WORDS_X)
            v = bits[((size_t)(b << 10) + gy) * WORDS_X + wi];
        s_w[r][k] = v;
    }

    // Pin x in VGPRs (loads were issued before the bit loads; in-order vmcnt
    // means this adds no wait, but stops the compiler sinking them).
#pragma unroll
    for (int q = 0; q < 4; ++q) {
        asm volatile("" :: "v"(xv0[q].x), "v"(xv0[q].y), "v"(xv0[q].z), "v"(xv0[q].w));
        asm volatile("" :: "v"(xv1[q].x), "v"(xv1[q].y), "v"(xv1[q].z), "v"(xv1[q].w));
    }
    __syncthreads();

    // ---- Horizontal 11-window OR/AND (funnel shift over 192 bits) ----
    if (tid < 74) {
        u64 wl = s_w[tid][0], wm = s_w[tid][1], wr = s_w[tid][2];
        u64 oh = wm, ah = wm;
#pragma unroll
        for (int d = 1; d <= 5; ++d) {
            u64 vr = (wm >> d) | (wr << (64 - d));
            u64 vl = (wm << d) | (wl >> (64 - d));
            oh |= vr | vl;
            ah &= vr & vl;
        }
        s_oh[tid] = oh;
        s_ah[tid] = ah;
    }
    __syncthreads();

    // ---- Vertical 11-window; per-row edge word ----
    if (tid < 64) {
        u64 ov = 0, av = ~0ULL;
#pragma unroll
        for (int k = 0; k < 11; ++k) { ov |= s_oh[tid + k]; av &= s_ah[tid + k]; }
        u64 tc = s_w[tid + 5][1];
        s_e[tid] = (ov & ~tc) | (~av & tc);
    }
    __syncthreads();

    // ---- Loss: 16 px/thread from pinned registers + 16 bits ----
    unsigned int e16 = (unsigned int)(s_e[row] >> c0) & 0xffffu;
    unsigned int t16 = (unsigned int)(s_w[row + 5][1] >> c0) & 0xffffu;

    const float* f0 = (const float*)xv0;
    const float* f1 = (const float*)xv1;
    float acc = 0.f;
#pragma unroll
    for (int j = 0; j < 16; ++j) {
        int t = (t16 >> j) & 1;
        int e = (e16 >> j) & 1;
        float v0 = f0[j], v1 = f1[j];
        float m   = fmaxf(v0, v1);
        float lse = m + __logf(1.0f + __expf(-fabsf(v0 - v1)));
        float lp0 = v0 - lse, lp1 = v1 - lse;
        float lpt = t ? lp1 : lp0;
        float lpo = t ? lp0 : lp1;
        acc += e ? (0.95f * lpt + 0.1f * lpo) : lpt;
    }

#pragma unroll
    for (int off = 32; off > 0; off >>= 1) acc += __shfl_down(acc, off, 64);
    if ((tid & 63) == 0) s_red[tid >> 6] = acc;
    __syncthreads();
    if (tid == 0) {
        int bid = (blockIdx.z * gridDim.y + blockIdx.y) * gridDim.x + blockIdx.x;
        partial[bid] = s_red[0] + s_red[1] + s_red[2] + s_red[3];
    }
}

__global__ __launch_bounds__(256) void ls_final(const float* __restrict__ partial,
                                                float* __restrict__ out) {
    __shared__ double s_red[4];
    const int tid = threadIdx.x;
    double s = 0.0;
    for (int i = tid; i < NPART; i += 256) s += (double)partial[i];
#pragma unroll
    for (int off = 32; off > 0; off >>= 1) s += __shfl_down(s, off, 64);
    if ((tid & 63) == 0) s_red[tid >> 6] = s;
    __syncthreads();
    if (tid == 0) {
        double total = s_red[0] + s_red[1] + s_red[2] + s_red[3];
        out[0] = (float)(-total * (1.0 / (8.0 * 1024.0 * 1024.0)));
    }
}

extern "C" void kernel_launch(void* const* d_in, const int* in_sizes, int n_in,
                              void* d_out, int out_size, void* d_ws, size_t ws_size,
                              hipStream_t stream) {
    const float* x  = (const float*)d_in[0];
    const int* tgt  = (const int*)d_in[1];

    // ws: [partials 8KB][bit image 1MB]
    float* partial = (float*)d_ws;
    u64* bits = (u64*)((char*)d_ws + (16 << 10));

    hipLaunchKernelGGL(ls_pack, dim3(4096), dim3(256), 0, stream, tgt, bits);
    hipLaunchKernelGGL(ls_loss, dim3(16, 16, 8), dim3(256), 0, stream, x, bits, partial);
    hipLaunchKernelGGL(ls_final, dim3(1), dim3(256), 0, stream, partial, (float*)d_out);
}